// Round 20
// baseline (232.757 us; speedup 1.0000x reference)
//
#include <hip/hip_runtime.h>
#include <hip/hip_cooperative_groups.h>
#include <stdint.h>

namespace cg = cooperative_groups;

typedef unsigned short u16;
typedef __attribute__((ext_vector_type(8))) short short8;
typedef __attribute__((ext_vector_type(4))) float f32x4;
typedef __attribute__((ext_vector_type(4))) unsigned int u32x4;

#define NTRACE 4096
#define TLEN   64
#define ISZ    64
#define HSZ    128
#define NBIN   64
#define VSZ    10000
#define NBLK   256
#define NWSLOT (NBLK * 4)

#define LOG2E     1.44269504088896f
#define TWOLOG2E  2.88539008177793f

__device__ __forceinline__ float bflo(uint32_t u) {
  union { uint32_t i; float f; } v; v.i = u << 16; return v.f;
}
__device__ __forceinline__ float bfhi(uint32_t u) {
  union { uint32_t i; float f; } v; v.i = u & 0xffff0000u; return v.f;
}
__device__ __forceinline__ u16 f2bf(float f) {
  union { float f; uint32_t i; } v; v.f = f;
  uint32_t r = v.i + 0x7fffu + ((v.i >> 16) & 1u);
  return (u16)(r >> 16);
}
__device__ __forceinline__ float fexp2(float x) {
  float r;
  asm("v_exp_f32 %0, %1" : "=v"(r) : "v"(x));
  return r;
}
// tanh(a)*sigmoid(b) with pre-scaled gates: gB=-log2e*b, gE=2log2e*a
__device__ __forceinline__ float gate2(float gB, float gE) {
  float E = fexp2(gE);
  float B = fexp2(gB);
  return (E - 1.0f) * __builtin_amdgcn_rcpf((E + 1.0f) * (1.0f + B));
}
__device__ __forceinline__ short8 mk8(uint32_t a, uint32_t b, uint32_t c, uint32_t d) {
  union { short8 s; uint32_t u[4]; } z;
  z.u[0] = a; z.u[1] = b; z.u[2] = c; z.u[3] = d; return z.s;
}
union S8 { short8 s; u16 h[8]; };
// Weight-row permutation (R6-VERIFIED): buffer tile-row rr holds true hidden
// index pi(rr); MFMA C output renames register-only into the next layer's
// B-fragment (linear k): frag ks elem j = h[ks*32+q*8+j].
__device__ __forceinline__ int perm128(int rr) {
  return ((rr >> 4) & 3) * 32 + ((rr >> 2) & 3) * 8 + ((rr >> 6) & 1) * 4 + (rr & 3);
}

// ---------------------------------------------------------------------------
// k_all: single cooperative kernel, 256 blocks x 256 thr (144 KB LDS ->
// 1 block/CU -> exactly co-resident). Four phases, each a VERBATIM verified
// body, separated by grid.sync() (the sanctioned grid barrier — fixes both
// prior fusion failures: R16/R18's per-block conversion redundancy and
// R18's ad-hoc threadfence+ctr tax):
//   P1 R17-k_prep  (grid-partitioned conversion, once; bins zero)
//   P2 R19-k_vocab (memoization: h1/h2/energy are pure functions of token
//                   id since h0=c0=0; 10000 vocab entries vs 262144 positions)
//   P3 R19-k_attn  (grid-stride, 4 traces per wave-slot)
//   P4 R17-k_out   (block 0: bins reduce + 128x128 matvec)
// ---------------------------------------------------------------------------
__global__ __launch_bounds__(256) void k_all(
    const float* __restrict__ emb,
    const float* __restrict__ W1, const float* __restrict__ W2,
    const float* __restrict__ b_ih1, const float* __restrict__ b_hh1,
    const float* __restrict__ b_ih2, const float* __restrict__ b_hh2,
    const float* __restrict__ Wp1,
    const float* __restrict__ bp1v, const float* __restrict__ wp2v,
    const float* __restrict__ W_out, const float* __restrict__ b_out,
    const int* __restrict__ traces, const int* __restrict__ lengths,
    u16* __restrict__ w1c, u16* __restrict__ w2c, u16* __restrict__ wp1b,
    float* __restrict__ bs1, float* __restrict__ bs2,
    float* __restrict__ bins,
    float* __restrict__ Et, u16* __restrict__ H2t,
    float* __restrict__ out)
{
  __shared__ __align__(16) u16 w1s[384 * 64];    //  48 KB
  __shared__ __align__(16) u16 w2s[384 * 128];   //  96 KB
  cg::grid_group grid = cg::this_grid();
  const int tid = threadIdx.x;

  // ==== Phase 1: prep (R17-k_prep verbatim; grid-partitioned, done ONCE)
  {
    const int i = blockIdx.x * 256 + tid;
    if (i < 3072) {       // w1: 384 compact rows x 64 u16
      const int r    = i >> 3;
      const int G3   = r >> 7;                    // 0:i 1:g 2:o
      const int rawG = (G3 == 0) ? 0 : ((G3 == 1) ? 2 : 3);
      const int src  = rawG * 128 + perm128(r & 127);
      const float s  = (G3 == 1) ? TWOLOG2E : -LOG2E;
      const int c16  = (i & 7) * 8;
      const float* wsrc = W1 + (size_t)src * ISZ + c16;
      uint32_t pkk[4];
#pragma unroll
      for (int k = 0; k < 4; ++k)
        pkk[k] = (uint32_t)f2bf(wsrc[2 * k] * s) |
                 ((uint32_t)f2bf(wsrc[2 * k + 1] * s) << 16);
      *(u32x4*)&w1c[r * 64 + (c16 ^ ((r & 7) << 3))] = *(u32x4*)pkk;
    }
    if (i < 6144) {       // w2: 384 compact rows x 128 u16
      const int r    = i >> 4;
      const int G3   = r >> 7;
      const int rawG = (G3 == 0) ? 0 : ((G3 == 1) ? 2 : 3);
      const int src  = rawG * 128 + perm128(r & 127);
      const float s  = (G3 == 1) ? TWOLOG2E : -LOG2E;
      const int c16  = (i & 15) * 8;
      const float* wsrc = W2 + (size_t)src * HSZ + c16;
      uint32_t pkk[4];
#pragma unroll
      for (int k = 0; k < 4; ++k)
        pkk[k] = (uint32_t)f2bf(wsrc[2 * k] * s) |
                 ((uint32_t)f2bf(wsrc[2 * k + 1] * s) << 16);
      *(u32x4*)&w2c[r * 128 + (c16 ^ ((r & 15) << 3))] = *(u32x4*)pkk;
    }
    if (i < 64 * 128) wp1b[i] = f2bf(Wp1[i]);
    if (i < 512) {
      const int G = i >> 7, rr = i & 127;
      const float s = (G == 2) ? TWOLOG2E : -LOG2E;
      const int src = G * 128 + perm128(rr);
      bs1[i] = (b_ih1[src] + b_hh1[src]) * s;
      bs2[i] = (b_ih2[src] + b_hh2[src]) * s;
    }
    if (i < NBIN * HSZ) bins[i] = 0.f;
  }
  grid.sync();

  // ==== Phase 2: vocab memoization (R19-k_vocab verbatim on active blocks)
  if (blockIdx.x * 64 < VSZ) {      // block covers ids [blockIdx*64, +64)
    // staging: pure linear 16B copies (layout already swizzled)
    for (int i = tid; i < 3072; i += 256)
      ((u32x4*)w1s)[i] = ((const u32x4*)w1c)[i];
    for (int i = tid; i < 6144; i += 256)
      ((u32x4*)w2s)[i] = ((const u32x4*)w2c)[i];
    __syncthreads();

    const int lane = tid & 63;
    const int col  = lane & 15;
    const int q    = lane >> 4;
    const int sw1  = (col & 7) << 3;
    const int sw2  = col << 3;
    const int id   = (blockIdx.x * 4 + (tid >> 6)) * 16 + col;  // 16 ids/wave
    const int idc  = (id < VSZ) ? id : 0;
    const f32x4 z = {0.f, 0.f, 0.f, 0.f};

    // x fragments: raw f32 emb, converted inline (R16/R17-proven)
    short8 xf[2];
    {
      const float* xr = emb + (size_t)idc * ISZ + q * 8;
#pragma unroll
      for (int ks = 0; ks < 2; ++ks) {
        S8 v;
#pragma unroll
        for (int k = 0; k < 8; ++k) v.h[k] = f2bf(xr[ks * 32 + k]);
        xf[ks] = v.s;
      }
    }

    // LSTM layer 1 (R11-verified structure, NG=1)
    uint32_t pk[8][2];
#pragma unroll
    for (int mt = 0; mt < 8; ++mt) {
      f32x4 aI = z, aC = z, aO = z;
#pragma unroll
      for (int ks = 0; ks < 2; ++ks) {
        const int off = ((ks * 32 + q * 8) ^ sw1);
        short8 fI = *(const short8*)&w1s[(mt * 16 + col) * ISZ + off];
        short8 fC = *(const short8*)&w1s[(128 + mt * 16 + col) * ISZ + off];
        short8 fO = *(const short8*)&w1s[(256 + mt * 16 + col) * ISZ + off];
        aI = __builtin_amdgcn_mfma_f32_16x16x32_bf16(fI, xf[ks], aI, 0, 0, 0);
        aC = __builtin_amdgcn_mfma_f32_16x16x32_bf16(fC, xf[ks], aC, 0, 0, 0);
        aO = __builtin_amdgcn_mfma_f32_16x16x32_bf16(fO, xf[ks], aO, 0, 0, 0);
      }
      u16 hv[4];
#pragma unroll
      for (int r = 0; r < 4; ++r) {
        const int h = mt * 16 + q * 4 + r;
        float c = gate2(aI[r] + bs1[h], aC[r] + bs1[256 + h]);
        hv[r] = f2bf(gate2(aO[r] + bs1[384 + h], TWOLOG2E * c));
      }
      pk[mt][0] = (uint32_t)hv[0] | ((uint32_t)hv[1] << 16);
      pk[mt][1] = (uint32_t)hv[2] | ((uint32_t)hv[3] << 16);
    }

    // h1 fragments: register rename (R6-verified)
    short8 hf[4];
#pragma unroll
    for (int ks = 0; ks < 4; ++ks)
      hf[ks] = mk8(pk[ks][0], pk[ks][1], pk[ks + 4][0], pk[ks + 4][1]);

    // LSTM layer 2 (R11-verified structure, NG=1)
    uint32_t pk2[8][2];
#pragma unroll
    for (int mt = 0; mt < 8; ++mt) {
      f32x4 aI = z, aC = z, aO = z;
#pragma unroll
      for (int ks = 0; ks < 4; ++ks) {
        const int off = ((ks * 32 + q * 8) ^ sw2);
        short8 fI = *(const short8*)&w2s[(mt * 16 + col) * HSZ + off];
        short8 fC = *(const short8*)&w2s[(128 + mt * 16 + col) * HSZ + off];
        short8 fO = *(const short8*)&w2s[(256 + mt * 16 + col) * HSZ + off];
        aI = __builtin_amdgcn_mfma_f32_16x16x32_bf16(fI, hf[ks], aI, 0, 0, 0);
        aC = __builtin_amdgcn_mfma_f32_16x16x32_bf16(fC, hf[ks], aC, 0, 0, 0);
        aO = __builtin_amdgcn_mfma_f32_16x16x32_bf16(fO, hf[ks], aO, 0, 0, 0);
      }
      u16 hv[4];
#pragma unroll
      for (int r = 0; r < 4; ++r) {
        const int h = mt * 16 + q * 4 + r;
        float c = gate2(aI[r] + bs2[h], aC[r] + bs2[256 + h]);
        hv[r] = f2bf(gate2(aO[r] + bs2[384 + h], TWOLOG2E * c));
      }
      pk2[mt][0] = (uint32_t)hv[0] | ((uint32_t)hv[1] << 16);
      pk2[mt][1] = (uint32_t)hv[2] | ((uint32_t)hv[3] << 16);
    }

    // h2 fragments (linear-k) via rename (R6-verified)
    short8 hf2[4];
#pragma unroll
    for (int ks = 0; ks < 4; ++ks)
      hf2[ks] = mk8(pk2[ks][0], pk2[ks][1], pk2[ks + 4][0], pk2[ks + 4][1]);

    // attention-MLP energy (R17 verbatim; wp1b global bf16)
    float ep = 0.f;
#pragma unroll
    for (int mt = 0; mt < 4; ++mt) {
      f32x4 acc = z;
#pragma unroll
      for (int ks = 0; ks < 4; ++ks) {
        short8 fA = *(const short8*)(wp1b + (size_t)(mt * 16 + col) * HSZ + ks * 32 + q * 8);
        acc = __builtin_amdgcn_mfma_f32_16x16x32_bf16(fA, hf2[ks], acc, 0, 0, 0);
      }
#pragma unroll
      for (int r = 0; r < 4; ++r) {
        const int hp = mt * 16 + q * 4 + r;
        ep += fmaxf(acc[r] + bp1v[hp], 0.f) * wp2v[hp];
      }
    }
    ep += __shfl_xor(ep, 16);
    ep += __shfl_xor(ep, 32);

    // table writes (bp2 omitted: constant shift cancels in softmax)
    if (id < VSZ) {
      if (q == 0) Et[id] = ep;
#pragma unroll
      for (int ks = 0; ks < 4; ++ks)
        *(short8*)&H2t[(size_t)id * HSZ + ks * 32 + q * 8] = hf2[ks];
    }
  }
  grid.sync();

  // ==== Phase 3: attention (R19-k_attn verbatim, grid-stride 4x)
  {
    const int wv   = tid >> 6;
    const int lane = tid & 63;
    const int slot = blockIdx.x * 4 + wv;
#pragma unroll 1
    for (int t = slot; t < NTRACE; t += NWSLOT) {
      const int len  = lengths[t];
      const int tok  = traces[t * TLEN + lane];
      const bool valid = lane < len;

      float e = valid ? Et[tok] : -3.0e38f;
      float m = e;
#pragma unroll
      for (int off = 1; off < 64; off <<= 1) m = fmaxf(m, __shfl_xor(m, off));
      float w = valid ? __expf(e - m) : 0.f;
      float s = w;
#pragma unroll
      for (int off = 1; off < 64; off <<= 1) s += __shfl_xor(s, off);
      const float wl = w * __builtin_amdgcn_rcpf(s);

      const int hc = lane * 2;
      const int ngrp = (len + 15) >> 4;    // wave-uniform
      float a0 = 0.f, a1 = 0.f;
      for (int g = 0; g < ngrp; ++g) {
#pragma unroll
        for (int i = 0; i < 16; ++i) {
          const int l = g * 16 + i;
          const float wb = __shfl(wl, l);  // 0 for l >= len
          const int   tb = __shfl(tok, l);
          const uint32_t hv = *(const uint32_t*)&H2t[(size_t)tb * HSZ + hc];
          a0 += wb * bflo(hv);
          a1 += wb * bfhi(hv);
        }
      }
      float* bin = bins + (size_t)(t & (NBIN - 1)) * HSZ;
      atomicAdd(&bin[hc], a0);
      atomicAdd(&bin[hc + 1], a1);
    }
  }
  grid.sync();

  // ==== Phase 4: out (R17-k_out verbatim; block 0; plain reads safe
  // after grid.sync)
  if (blockIdx.x == 0) {
    float* fs = (float*)w1s;           // reuse LDS
    const int o = tid;
    if (o < HSZ) {
      float s = 0.f;
#pragma unroll 4
      for (int b = 0; b < NBIN; ++b) s += bins[b * HSZ + o];
      fs[o] = s;
    }
    __syncthreads();
    if (o < HSZ) {
      float acc = b_out[o];
      const float* wr = W_out + (size_t)o * HSZ;
#pragma unroll
      for (int h = 0; h < HSZ; ++h) acc += wr[h] * fs[h];
      out[o] = acc;
    }
  }
}

extern "C" void kernel_launch(void* const* d_in, const int* in_sizes, int n_in,
                              void* d_out, int out_size, void* d_ws, size_t ws_size,
                              hipStream_t stream)
{
  const float* emb   = (const float*)d_in[0];
  const float* W_ih1 = (const float*)d_in[1];
  // d_in[2] = W_hh1: unused (h0 = 0)
  const float* b_ih1 = (const float*)d_in[3];
  const float* b_hh1 = (const float*)d_in[4];
  const float* W_ih2 = (const float*)d_in[5];
  // d_in[6] = W_hh2: unused
  const float* b_ih2 = (const float*)d_in[7];
  const float* b_hh2 = (const float*)d_in[8];
  const float* Wp1   = (const float*)d_in[9];
  const float* bp1   = (const float*)d_in[10];
  const float* Wp2   = (const float*)d_in[11];
  const float* bp2   = (const float*)d_in[12];  // cancels in softmax: unused
  const float* W_out = (const float*)d_in[13];
  const float* b_out = (const float*)d_in[14];
  const int* traces  = (const int*)d_in[15];
  const int* lengths = (const int*)d_in[16];
  (void)bp2;

  char* ws = (char*)d_ws;
  float* Et   = (float*)(ws);                // 10240*4     = 40960 B
  u16*   H2t  = (u16*)(ws + 40960);          // 10240*128*2 = 2621440 B
  float* bins = (float*)(ws + 2662400);      // 64*128*4    = 32768 B
  u16*   w1c  = (u16*)(ws + 2695168);        // 384*64*2    = 49152 B
  u16*   w2c  = (u16*)(ws + 2744320);        // 384*128*2   = 98304 B
  u16*   wp1b = (u16*)(ws + 2842624);        // 64*128*2    = 16384 B
  float* bs1  = (float*)(ws + 2859008);      // 2048 B
  float* bs2  = (float*)(ws + 2861056);      // 2048 B
  float* outp = (float*)d_out;

  void* args[] = {
    (void*)&emb, (void*)&W_ih1, (void*)&W_ih2,
    (void*)&b_ih1, (void*)&b_hh1, (void*)&b_ih2, (void*)&b_hh2,
    (void*)&Wp1, (void*)&bp1, (void*)&Wp2,
    (void*)&W_out, (void*)&b_out, (void*)&traces, (void*)&lengths,
    (void*)&w1c, (void*)&w2c, (void*)&wp1b, (void*)&bs1, (void*)&bs2,
    (void*)&bins, (void*)&Et, (void*)&H2t, (void*)&outp
  };
  hipLaunchCooperativeKernel((const void*)k_all, dim3(NBLK), dim3(256),
                             args, 0, stream);
}

// Round 21
// 122.132 us; speedup vs baseline: 1.9058x; 1.9058x over previous
//
#include <hip/hip_runtime.h>
#include <stdint.h>

typedef unsigned short u16;
typedef __attribute__((ext_vector_type(8))) short short8;
typedef __attribute__((ext_vector_type(4))) float f32x4;
typedef __attribute__((ext_vector_type(4))) unsigned int u32x4;

#define NTRACE 4096
#define TLEN   64
#define ISZ    64
#define HSZ    128
#define NBIN   64
#define VSZ    10000

#define LOG2E     1.44269504088896f
#define TWOLOG2E  2.88539008177793f

__device__ __forceinline__ float bflo(uint32_t u) {
  union { uint32_t i; float f; } v; v.i = u << 16; return v.f;
}
__device__ __forceinline__ float bfhi(uint32_t u) {
  union { uint32_t i; float f; } v; v.i = u & 0xffff0000u; return v.f;
}
__device__ __forceinline__ u16 f2bf(float f) {
  union { float f; uint32_t i; } v; v.f = f;
  uint32_t r = v.i + 0x7fffu + ((v.i >> 16) & 1u);
  return (u16)(r >> 16);
}
__device__ __forceinline__ float fexp2(float x) {
  float r;
  asm("v_exp_f32 %0, %1" : "=v"(r) : "v"(x));
  return r;
}
// tanh(a)*sigmoid(b) with pre-scaled gates: gB=-log2e*b, gE=2log2e*a
__device__ __forceinline__ float gate2(float gB, float gE) {
  float E = fexp2(gE);
  float B = fexp2(gB);
  return (E - 1.0f) * __builtin_amdgcn_rcpf((E + 1.0f) * (1.0f + B));
}
__device__ __forceinline__ short8 mk8(uint32_t a, uint32_t b, uint32_t c, uint32_t d) {
  union { short8 s; uint32_t u[4]; } z;
  z.u[0] = a; z.u[1] = b; z.u[2] = c; z.u[3] = d; return z.s;
}
union S8 { short8 s; u16 h[8]; };
// Weight-row permutation (R6-VERIFIED): buffer tile-row rr holds true hidden
// index pi(rr); MFMA C output renames register-only into the next layer's
// B-fragment (linear k): frag ks elem j = h[ks*32+q*8+j].
__device__ __forceinline__ int perm128(int rr) {
  return ((rr >> 4) & 3) * 32 + ((rr >> 2) & 3) * 8 + ((rr >> 6) & 1) * 4 + (rr & 3);
}

// ---------------------------------------------------------------------------
// k_prep (R17-VERIFIED, verbatim): writes the COMPACT weight image (gates
// {i,g,o}, pi-permuted rows, exp2 scale-folded, XOR-swizzled) so k_vocab's
// staging is a pure 16B copy. Plus wp1 bf16, bias sums, bins zero.
// ---------------------------------------------------------------------------
__global__ __launch_bounds__(256) void k_prep(
    const float* __restrict__ W1, const float* __restrict__ W2,
    const float* __restrict__ Wp1,
    const float* __restrict__ b_ih1, const float* __restrict__ b_hh1,
    const float* __restrict__ b_ih2, const float* __restrict__ b_hh2,
    u16* __restrict__ w1c, u16* __restrict__ w2c, u16* __restrict__ wp1b,
    float* __restrict__ bs1, float* __restrict__ bs2,
    float* __restrict__ bins)
{
  const int i = blockIdx.x * 256 + threadIdx.x;   // 8192 threads
  if (i < 3072) {       // w1: 384 compact rows x 64 u16 (8 u16 per item)
    const int r    = i >> 3;
    const int G3   = r >> 7;                      // 0:i 1:g 2:o
    const int rawG = (G3 == 0) ? 0 : ((G3 == 1) ? 2 : 3);
    const int src  = rawG * 128 + perm128(r & 127);
    const float s  = (G3 == 1) ? TWOLOG2E : -LOG2E;
    const int c16  = (i & 7) * 8;
    const float* wsrc = W1 + (size_t)src * ISZ + c16;
    uint32_t pkk[4];
#pragma unroll
    for (int k = 0; k < 4; ++k)
      pkk[k] = (uint32_t)f2bf(wsrc[2 * k] * s) |
               ((uint32_t)f2bf(wsrc[2 * k + 1] * s) << 16);
    *(u32x4*)&w1c[r * 64 + (c16 ^ ((r & 7) << 3))] = *(u32x4*)pkk;
  }
  if (i < 6144) {       // w2: 384 compact rows x 128 u16
    const int r    = i >> 4;
    const int G3   = r >> 7;
    const int rawG = (G3 == 0) ? 0 : ((G3 == 1) ? 2 : 3);
    const int src  = rawG * 128 + perm128(r & 127);
    const float s  = (G3 == 1) ? TWOLOG2E : -LOG2E;
    const int c16  = (i & 15) * 8;
    const float* wsrc = W2 + (size_t)src * HSZ + c16;
    uint32_t pkk[4];
#pragma unroll
    for (int k = 0; k < 4; ++k)
      pkk[k] = (uint32_t)f2bf(wsrc[2 * k] * s) |
               ((uint32_t)f2bf(wsrc[2 * k + 1] * s) << 16);
    *(u32x4*)&w2c[r * 128 + (c16 ^ ((r & 15) << 3))] = *(u32x4*)pkk;
  }
  if (i < 64 * 128) wp1b[i] = f2bf(Wp1[i]);
  if (i < 512) {
    const int G = i >> 7, rr = i & 127;
    const float s = (G == 2) ? TWOLOG2E : -LOG2E;
    const int src = G * 128 + perm128(rr);
    bs1[i] = (b_ih1[src] + b_hh1[src]) * s;
    bs2[i] = (b_ih2[src] + b_hh2[src]) * s;
  }
  if (i < NBIN * HSZ) bins[i] = 0.f;
}

// ---------------------------------------------------------------------------
// k_vocab (R19-VERIFIED, verbatim): memoization kernel, NG=1. h0=c0=0 =>
// h1, h2, energy are pure functions of TOKEN ID: compute per vocab entry
// (10000), not per position (262144). 160 blocks x 256 thr (4 waves x 16
// ids = 10240 >= VSZ). Staging = pure 16B copy of the prepped image.
// ---------------------------------------------------------------------------
__global__ __launch_bounds__(256) void k_vocab(
    const float* __restrict__ emb,
    const u16* __restrict__ w1c, const u16* __restrict__ w2c,
    const float* __restrict__ bs1, const float* __restrict__ bs2,
    const u16* __restrict__ wp1b,
    const float* __restrict__ bp1v, const float* __restrict__ wp2v,
    float* __restrict__ Et, u16* __restrict__ H2t)
{
  __shared__ __align__(16) u16 w1s[384 * 64];    //  48 KB
  __shared__ __align__(16) u16 w2s[384 * 128];   //  96 KB
  const int tid = threadIdx.x;

  // ---- staging: pure linear 16B copies (layout already swizzled)
  for (int i = tid; i < 3072; i += 256)
    ((u32x4*)w1s)[i] = ((const u32x4*)w1c)[i];
  for (int i = tid; i < 6144; i += 256)
    ((u32x4*)w2s)[i] = ((const u32x4*)w2c)[i];
  __syncthreads();

  const int lane = tid & 63;
  const int col  = lane & 15;
  const int q    = lane >> 4;
  const int sw1  = (col & 7) << 3;
  const int sw2  = col << 3;
  const int id   = (blockIdx.x * 4 + (tid >> 6)) * 16 + col;  // 16 ids/wave
  const int idc  = (id < VSZ) ? id : 0;
  const f32x4 z = {0.f, 0.f, 0.f, 0.f};

  // ---- x fragments: raw f32 emb, converted inline (R16/R17-proven)
  short8 xf[2];
  {
    const float* xr = emb + (size_t)idc * ISZ + q * 8;
#pragma unroll
    for (int ks = 0; ks < 2; ++ks) {
      S8 v;
#pragma unroll
      for (int k = 0; k < 8; ++k) v.h[k] = f2bf(xr[ks * 32 + k]);
      xf[ks] = v.s;
    }
  }

  // ---- LSTM layer 1 (R11-verified structure, NG=1)
  uint32_t pk[8][2];
#pragma unroll
  for (int mt = 0; mt < 8; ++mt) {
    f32x4 aI = z, aC = z, aO = z;
#pragma unroll
    for (int ks = 0; ks < 2; ++ks) {
      const int off = ((ks * 32 + q * 8) ^ sw1);
      short8 fI = *(const short8*)&w1s[(mt * 16 + col) * ISZ + off];
      short8 fC = *(const short8*)&w1s[(128 + mt * 16 + col) * ISZ + off];
      short8 fO = *(const short8*)&w1s[(256 + mt * 16 + col) * ISZ + off];
      aI = __builtin_amdgcn_mfma_f32_16x16x32_bf16(fI, xf[ks], aI, 0, 0, 0);
      aC = __builtin_amdgcn_mfma_f32_16x16x32_bf16(fC, xf[ks], aC, 0, 0, 0);
      aO = __builtin_amdgcn_mfma_f32_16x16x32_bf16(fO, xf[ks], aO, 0, 0, 0);
    }
    u16 hv[4];
#pragma unroll
    for (int r = 0; r < 4; ++r) {
      const int h = mt * 16 + q * 4 + r;
      float c = gate2(aI[r] + bs1[h], aC[r] + bs1[256 + h]);
      hv[r] = f2bf(gate2(aO[r] + bs1[384 + h], TWOLOG2E * c));
    }
    pk[mt][0] = (uint32_t)hv[0] | ((uint32_t)hv[1] << 16);
    pk[mt][1] = (uint32_t)hv[2] | ((uint32_t)hv[3] << 16);
  }

  // ---- h1 fragments: register rename (R6-verified)
  short8 hf[4];
#pragma unroll
  for (int ks = 0; ks < 4; ++ks)
    hf[ks] = mk8(pk[ks][0], pk[ks][1], pk[ks + 4][0], pk[ks + 4][1]);

  // ---- LSTM layer 2 (R11-verified structure, NG=1)
  uint32_t pk2[8][2];
#pragma unroll
  for (int mt = 0; mt < 8; ++mt) {
    f32x4 aI = z, aC = z, aO = z;
#pragma unroll
    for (int ks = 0; ks < 4; ++ks) {
      const int off = ((ks * 32 + q * 8) ^ sw2);
      short8 fI = *(const short8*)&w2s[(mt * 16 + col) * HSZ + off];
      short8 fC = *(const short8*)&w2s[(128 + mt * 16 + col) * HSZ + off];
      short8 fO = *(const short8*)&w2s[(256 + mt * 16 + col) * HSZ + off];
      aI = __builtin_amdgcn_mfma_f32_16x16x32_bf16(fI, hf[ks], aI, 0, 0, 0);
      aC = __builtin_amdgcn_mfma_f32_16x16x32_bf16(fC, hf[ks], aC, 0, 0, 0);
      aO = __builtin_amdgcn_mfma_f32_16x16x32_bf16(fO, hf[ks], aO, 0, 0, 0);
    }
    u16 hv[4];
#pragma unroll
    for (int r = 0; r < 4; ++r) {
      const int h = mt * 16 + q * 4 + r;
      float c = gate2(aI[r] + bs2[h], aC[r] + bs2[256 + h]);
      hv[r] = f2bf(gate2(aO[r] + bs2[384 + h], TWOLOG2E * c));
    }
    pk2[mt][0] = (uint32_t)hv[0] | ((uint32_t)hv[1] << 16);
    pk2[mt][1] = (uint32_t)hv[2] | ((uint32_t)hv[3] << 16);
  }

  // ---- h2 fragments (linear-k) via rename (R6-verified)
  short8 hf2[4];
#pragma unroll
  for (int ks = 0; ks < 4; ++ks)
    hf2[ks] = mk8(pk2[ks][0], pk2[ks][1], pk2[ks + 4][0], pk2[ks + 4][1]);

  // ---- attention-MLP energy (R17 verbatim; wp1b global bf16)
  float ep = 0.f;
#pragma unroll
  for (int mt = 0; mt < 4; ++mt) {
    f32x4 acc = z;
#pragma unroll
    for (int ks = 0; ks < 4; ++ks) {
      short8 fA = *(const short8*)(wp1b + (size_t)(mt * 16 + col) * HSZ + ks * 32 + q * 8);
      acc = __builtin_amdgcn_mfma_f32_16x16x32_bf16(fA, hf2[ks], acc, 0, 0, 0);
    }
#pragma unroll
    for (int r = 0; r < 4; ++r) {
      const int hp = mt * 16 + q * 4 + r;
      ep += fmaxf(acc[r] + bp1v[hp], 0.f) * wp2v[hp];
    }
  }
  ep += __shfl_xor(ep, 16);
  ep += __shfl_xor(ep, 32);

  // ---- table writes (bp2 omitted: constant shift cancels in softmax)
  if (id < VSZ) {
    if (q == 0) Et[id] = ep;
#pragma unroll
    for (int ks = 0; ks < 4; ++ks)
      *(short8*)&H2t[(size_t)id * HSZ + ks * 32 + q * 8] = hf2[ks];
  }
}

// ---------------------------------------------------------------------------
// k_attn (R19-VERIFIED, verbatim): per-trace gather + softmax + weighted
// sum. l-loop padded to 16-groups and inner-unrolled so 16 independent H2
// row reads are in flight. Padded lanes have wl == 0 (masked in softmax)
// and traces[] rows are fully populated, so padded terms contribute 0.
// ---------------------------------------------------------------------------
__global__ __launch_bounds__(256) void k_attn(
    const float* __restrict__ Et, const u16* __restrict__ H2t,
    const int* __restrict__ traces, const int* __restrict__ lengths,
    float* __restrict__ bins)
{
  const int wv   = threadIdx.x >> 6;
  const int lane = threadIdx.x & 63;
  const int t    = blockIdx.x * 4 + wv;
  const int len  = lengths[t];
  const int tok  = traces[t * TLEN + lane];
  const bool valid = lane < len;

  float e = valid ? Et[tok] : -3.0e38f;
  float m = e;
#pragma unroll
  for (int off = 1; off < 64; off <<= 1) m = fmaxf(m, __shfl_xor(m, off));
  float w = valid ? __expf(e - m) : 0.f;
  float s = w;
#pragma unroll
  for (int off = 1; off < 64; off <<= 1) s += __shfl_xor(s, off);
  const float wl = w * __builtin_amdgcn_rcpf(s);

  const int hc = lane * 2;
  const int ngrp = (len + 15) >> 4;        // wave-uniform
  float a0 = 0.f, a1 = 0.f;
  for (int g = 0; g < ngrp; ++g) {
#pragma unroll
    for (int i = 0; i < 16; ++i) {
      const int l = g * 16 + i;
      const float wb = __shfl(wl, l);      // 0 for l >= len
      const int   tb = __shfl(tok, l);
      const uint32_t hv = *(const uint32_t*)&H2t[(size_t)tb * HSZ + hc];
      a0 += wb * bflo(hv);
      a1 += wb * bfhi(hv);
    }
  }
  float* bin = bins + (size_t)(t & (NBIN - 1)) * HSZ;
  atomicAdd(&bin[hc], a0);
  atomicAdd(&bin[hc + 1], a1);
}

// ---------------------------------------------------------------------------
// k_out (R6-VERIFIED, verbatim): reduce 64 bins -> fin, then 128x128 matvec.
// ---------------------------------------------------------------------------
__global__ __launch_bounds__(128) void k_out(
    const float* __restrict__ bins, const float* __restrict__ W_out,
    const float* __restrict__ b_out, float* __restrict__ out)
{
  const int o = threadIdx.x;      // 0..127
  __shared__ float fs[HSZ];
  float s = 0.f;
#pragma unroll 4
  for (int b = 0; b < NBIN; ++b) s += bins[b * HSZ + o];
  fs[o] = s;
  __syncthreads();
  float acc = b_out[o];
  const float* wr = W_out + (size_t)o * HSZ;
#pragma unroll
  for (int h = 0; h < HSZ; ++h) acc += wr[h] * fs[h];
  out[o] = acc;
}

extern "C" void kernel_launch(void* const* d_in, const int* in_sizes, int n_in,
                              void* d_out, int out_size, void* d_ws, size_t ws_size,
                              hipStream_t stream)
{
  const float* emb   = (const float*)d_in[0];
  const float* W_ih1 = (const float*)d_in[1];
  // d_in[2] = W_hh1: unused (h0 = 0)
  const float* b_ih1 = (const float*)d_in[3];
  const float* b_hh1 = (const float*)d_in[4];
  const float* W_ih2 = (const float*)d_in[5];
  // d_in[6] = W_hh2: unused
  const float* b_ih2 = (const float*)d_in[7];
  const float* b_hh2 = (const float*)d_in[8];
  const float* Wp1   = (const float*)d_in[9];
  const float* bp1   = (const float*)d_in[10];
  const float* Wp2   = (const float*)d_in[11];
  const float* bp2   = (const float*)d_in[12];  // cancels in softmax: unused
  const float* W_out = (const float*)d_in[13];
  const float* b_out = (const float*)d_in[14];
  const int* traces  = (const int*)d_in[15];
  const int* lengths = (const int*)d_in[16];
  (void)bp2;

  char* ws = (char*)d_ws;
  float* Et   = (float*)(ws);                // 10240*4     = 40960 B
  u16*   H2t  = (u16*)(ws + 40960);          // 10240*128*2 = 2621440 B
  float* bins = (float*)(ws + 2662400);      // 64*128*4    = 32768 B
  u16*   w1c  = (u16*)(ws + 2695168);        // 384*64*2    = 49152 B
  u16*   w2c  = (u16*)(ws + 2744320);        // 384*128*2   = 98304 B
  u16*   wp1b = (u16*)(ws + 2842624);        // 64*128*2    = 16384 B
  float* bs1  = (float*)(ws + 2859008);      // 2048 B
  float* bs2  = (float*)(ws + 2861056);      // 2048 B

  k_prep<<<32, 256, 0, stream>>>(W_ih1, W_ih2, Wp1, b_ih1, b_hh1,
                                 b_ih2, b_hh2, w1c, w2c, wp1b,
                                 bs1, bs2, bins);
  k_vocab<<<160, 256, 0, stream>>>(emb, w1c, w2c, bs1, bs2, wp1b,
                                   bp1, Wp2, Et, H2t);
  k_attn<<<NTRACE / 4, 256, 0, stream>>>(Et, H2t, traces, lengths, bins);
  k_out<<<1, 128, 0, stream>>>(bins, W_out, b_out, (float*)d_out);
}